// Round 6
// baseline (460.091 us; speedup 1.0000x reference)
//
#include <hip/hip_runtime.h>
#include <hip/hip_bf16.h>
#include <stdint.h>

typedef unsigned short u16;
typedef __bf16 bf16x8 __attribute__((ext_vector_type(8)));
typedef float  f32x4  __attribute__((ext_vector_type(4)));
typedef u16    u16x8  __attribute__((ext_vector_type(8)));

__device__ __forceinline__ float bf2f(u16 u) {
    return __uint_as_float(((unsigned)u) << 16);
}
__device__ __forceinline__ u16 f2bf(float f) {   // round-to-nearest-even
    unsigned u = __float_as_uint(f);
    u += 0x7fffu + ((u >> 16) & 1u);
    return (u16)(u >> 16);
}

#define MFMA16(a, b, c) __builtin_amdgcn_mfma_f32_16x16x32_bf16(a, b, c, 0, 0, 0)

// Static device buffers — no d_ws dependency at all.
__device__ u16   h2g_buf[262144 * 64];   // h2 [N][64] bf16 (33.5 MB)
__device__ u16   w3b[64 * 64];           // weights pre-converted to bf16
__device__ u16   w4b[128 * 64];
__device__ u16   w5b[1024 * 192];
__device__ float g_buf[1024];            // global column max (>= 0)
__device__ float f1_buf[512];
__device__ float f2_buf[256];

// ---------------------------------------------------------------------------
__global__ void k0_zero() { g_buf[threadIdx.x] = 0.f; }

// convert w3/w4/w5 (f32) -> bf16 statics.  grid: 816 x 256 = 208896 threads.
__global__ void kcvt(const float* __restrict__ w3f, const float* __restrict__ w4f,
                     const float* __restrict__ w5f)
{
    int i = blockIdx.x * 256 + threadIdx.x;
    if (i < 4096)        w3b[i]         = f2bf(w3f[i]);
    else if (i < 12288)  w4b[i - 4096]  = f2bf(w4f[i - 4096]);
    else                 w5b[i - 12288] = f2bf(w5f[i - 12288]);
}

// ---------------------------------------------------------------------------
// k1: mlp1+mlp2 for 64 points/block (f32 inputs -> bf16 in LDS).
//     h1 = relu(x@w1^T) via VALU (K=3); h2 = relu(h1@w2^T) via MFMA.
// ---------------------------------------------------------------------------
__global__ __launch_bounds__(256) void k1_mlp(
    const float* __restrict__ xf, const float* __restrict__ w1f,
    const float* __restrict__ w2f)
{
    __shared__ __align__(16) u16 sw1[64 * 4];
    __shared__ __align__(16) u16 sx [64 * 4];
    __shared__ __align__(16) u16 sw2[64 * 72];   // stride 72: 16B rows, 2-way banks (free)
    __shared__ __align__(16) u16 shA[64 * 72];   // h1
    __shared__ __align__(16) u16 sh2[64 * 72];   // h2

    const int tid = threadIdx.x;
    const int p0  = blockIdx.x * 64;

    for (int i = tid; i < 64 * 64; i += 256)
        sw2[(i >> 6) * 72 + (i & 63)] = f2bf(w2f[i]);
    if (tid < 192) {
        sw1[(tid / 3) * 4 + tid % 3] = f2bf(w1f[tid]);
        sx [(tid / 3) * 4 + tid % 3] = f2bf(xf[p0 * 3 + tid]);
    }
    __syncthreads();

    // --- L1 via VALU (K=3): thread t -> point t&63, out cols (t>>6)*16.. ---
    {
        int m = tid & 63, ng = tid >> 6;
        float x0 = bf2f(sx[m * 4]), x1 = bf2f(sx[m * 4 + 1]), x2 = bf2f(sx[m * 4 + 2]);
        #pragma unroll
        for (int j = 0; j < 16; ++j) {
            int n = ng * 16 + j;
            float s = x0 * bf2f(sw1[n * 4]) + x1 * bf2f(sw1[n * 4 + 1]) + x2 * bf2f(sw1[n * 4 + 2]);
            shA[m * 72 + n] = f2bf(fmaxf(s, 0.f));
        }
    }
    __syncthreads();

    const int lane = tid & 63, w = tid >> 6, q = lane >> 4, l15 = lane & 15;
    const int mrow = 16 * w;

    // --- L2: h2 = relu(h1 @ w2^T) ---
    f32x4 acc2[4];
    #pragma unroll
    for (int nt = 0; nt < 4; ++nt) acc2[nt] = (f32x4){0.f, 0.f, 0.f, 0.f};
    #pragma unroll
    for (int s = 0; s < 2; ++s) {
        bf16x8 a = *(const bf16x8*)&shA[(mrow + l15) * 72 + s * 32 + q * 8];
        #pragma unroll
        for (int nt = 0; nt < 4; ++nt) {
            bf16x8 b = *(const bf16x8*)&sw2[(nt * 16 + l15) * 72 + s * 32 + q * 8];
            acc2[nt] = MFMA16(a, b, acc2[nt]);
        }
    }
    #pragma unroll
    for (int nt = 0; nt < 4; ++nt)
        #pragma unroll
        for (int r = 0; r < 4; ++r) {
            int m = mrow + q * 4 + r;
            sh2[m * 72 + nt * 16 + l15] = f2bf(fmaxf(acc2[nt][r], 0.f));
        }
    __syncthreads();

    // cooperative vectorized store of the 64x64 h2 tile (contiguous 8 KB)
    {
        int row = tid >> 2, c = (tid & 3) * 16;
        *(u16x8*)&h2g_buf[(size_t)p0 * 64 + tid * 16]     = *(const u16x8*)&sh2[row * 72 + c];
        *(u16x8*)&h2g_buf[(size_t)p0 * 64 + tid * 16 + 8] = *(const u16x8*)&sh2[row * 72 + c + 8];
    }
}

// ---------------------------------------------------------------------------
// k3: per 128-row block (all bf16 operands from statics):
//     P1 stage h2 tile [128][64] -> sB (XOR-swizzled)
//     P2 neighbor max-pool gather (fixed degree 16) -> sA cols 0..63
//     P4 h3 = relu(h2@w3^T) -> sB ; P5 h4 = relu(h3@w4^T) -> sA cols 64..191
//     main: h5 = relu([x_gm|h4] @ w5^T) fused with global column max.
//     atomicMax(int) valid: relu >= 0, g 0-init.
// ---------------------------------------------------------------------------
__global__ __launch_bounds__(256) void k3_fused(
    const int* __restrict__ indices, int* __restrict__ g)
{
    __shared__ __align__(16) u16 lds[128 * 192 + 128 * 64];   // 48 KB + 16 KB
    u16* sA = lds;                 // [128][192]: (r,k) -> r*192 + P*8 + (k&7),
                                   //   P = (j&24)|((j^r)&7), j = k>>3
    u16* sB = lds + 128 * 192;     // [128][64]:  (r,k) -> r*64 + ((j^r)&7)*8 + (k&7)

    const int tid  = threadIdx.x;
    const size_t R0 = (size_t)blockIdx.x * 128;
    const int lane = tid & 63, w = tid >> 6, q = lane >> 4, l15 = lane & 15;
    const int m0w  = (w & 1) * 64, n0w = (w >> 1) * 64;

    // ---- P1: stage h2 tile ----
    #pragma unroll
    for (int c = 0; c < 4; ++c) {
        int i = c * 256 + tid;
        int r = i >> 3, js = i & 7;
        *(u16x8*)&sB[r * 64 + ((js ^ r) & 7) * 8] =
            *(const u16x8*)&h2g_buf[(R0 + r) * 64 + js * 8];
    }

    // ---- P2: gather max over 16 neighbors -> sA cols 0..63 ----
    for (int rr = 0; rr < 32; ++rr) {
        int r  = w * 32 + rr;
        int jv = (lane < 16) ? indices[(R0 + r) * 16 + lane] : 0;
        float m = 0.f;                               // relu values >= 0
        #pragma unroll
        for (int k = 0; k < 16; ++k) {
            int j = __shfl(jv, k, 64);
            m = fmaxf(m, bf2f(h2g_buf[(size_t)j * 64 + lane]));
        }
        int p = ((lane >> 3) ^ r) & 7;
        sA[r * 192 + p * 8 + (lane & 7)] = f2bf(m);  // exact: max of bf16 values
    }
    __syncthreads();

    // ---- P4: h3 = relu(h2 @ w3^T), wave-local rows, write back into sB ----
    {
        f32x4 a3[2][4];
        #pragma unroll
        for (int mt = 0; mt < 2; ++mt)
            #pragma unroll
            for (int nt = 0; nt < 4; ++nt) a3[mt][nt] = (f32x4){0.f, 0.f, 0.f, 0.f};
        #pragma unroll
        for (int s = 0; s < 2; ++s) {
            bf16x8 a[2], b[4];
            #pragma unroll
            for (int mt = 0; mt < 2; ++mt) {
                int r = w * 32 + mt * 16 + l15;
                a[mt] = *(const bf16x8*)&sB[r * 64 + (((s * 4 + q) ^ r) & 7) * 8];
            }
            #pragma unroll
            for (int nt = 0; nt < 4; ++nt)
                b[nt] = *(const bf16x8*)&w3b[(nt * 16 + l15) * 64 + s * 32 + q * 8];
            #pragma unroll
            for (int mt = 0; mt < 2; ++mt)
                #pragma unroll
                for (int nt = 0; nt < 4; ++nt)
                    a3[mt][nt] = MFMA16(a[mt], b[nt], a3[mt][nt]);
        }
        __syncthreads();               // all h2 reads done before h3 overwrites sB
        #pragma unroll
        for (int mt = 0; mt < 2; ++mt)
            #pragma unroll
            for (int nt = 0; nt < 4; ++nt)
                #pragma unroll
                for (int r = 0; r < 4; ++r) {
                    int m = w * 32 + mt * 16 + q * 4 + r;
                    int n = nt * 16 + l15;
                    sB[m * 64 + (((n >> 3) ^ m) & 7) * 8 + (n & 7)] =
                        f2bf(fmaxf(a3[mt][nt][r], 0.f));
                }
    }
    __syncthreads();                   // h3 visible

    // ---- P5: h4 = relu(h3 @ w4^T) -> sA cols 64..191 ----
    {
        f32x4 a4[2][8];
        #pragma unroll
        for (int mt = 0; mt < 2; ++mt)
            #pragma unroll
            for (int nt = 0; nt < 8; ++nt) a4[mt][nt] = (f32x4){0.f, 0.f, 0.f, 0.f};
        #pragma unroll
        for (int s = 0; s < 2; ++s) {
            bf16x8 a[2];
            #pragma unroll
            for (int mt = 0; mt < 2; ++mt) {
                int r = w * 32 + mt * 16 + l15;
                a[mt] = *(const bf16x8*)&sB[r * 64 + (((s * 4 + q) ^ r) & 7) * 8];
            }
            #pragma unroll
            for (int nt = 0; nt < 8; ++nt) {
                bf16x8 b = *(const bf16x8*)&w4b[(nt * 16 + l15) * 64 + s * 32 + q * 8];
                #pragma unroll
                for (int mt = 0; mt < 2; ++mt)
                    a4[mt][nt] = MFMA16(a[mt], b, a4[mt][nt]);
            }
        }
        #pragma unroll
        for (int mt = 0; mt < 2; ++mt)
            #pragma unroll
            for (int nt = 0; nt < 8; ++nt)
                #pragma unroll
                for (int r = 0; r < 4; ++r) {
                    int m  = w * 32 + mt * 16 + q * 4 + r;
                    int n4 = nt * 16 + l15;            // 0..127 -> A col 64+n4
                    int j  = 8 + (n4 >> 3);            // logical chunk 8..23
                    int p  = (j & 24) | ((j ^ m) & 7);
                    sA[m * 192 + p * 8 + (n4 & 7)] = f2bf(fmaxf(a4[mt][nt][r], 0.f));
                }
    }

    // ---- main loop: relu([x_gm|h4] @ w5^T) + fused global column max ----
    for (int bn = 0; bn < 8; ++bn) {
        f32x4 acc[4][4];
        #pragma unroll
        for (int mt = 0; mt < 4; ++mt)
            #pragma unroll
            for (int nt = 0; nt < 4; ++nt) acc[mt][nt] = (f32x4){0.f, 0.f, 0.f, 0.f};

        for (int kt = 0; kt < 3; ++kt) {
            __syncthreads();           // P5/h3 reads done; prev sB reads done
            #pragma unroll
            for (int c = 0; c < 4; ++c) {
                int i = c * 256 + tid;
                int r = i >> 3, js = i & 7;
                *(u16x8*)&sB[r * 64 + ((js ^ r) & 7) * 8] =
                    *(const u16x8*)&w5b[(size_t)(bn * 128 + r) * 192 + kt * 64 + js * 8];
            }
            __syncthreads();
            #pragma unroll
            for (int s = 0; s < 2; ++s) {
                bf16x8 a[4], b[4];
                #pragma unroll
                for (int mt = 0; mt < 4; ++mt) {
                    int r = m0w + mt * 16 + l15;
                    int p = (kt * 8) | (((s * 4 + q) ^ r) & 7);
                    a[mt] = *(const bf16x8*)&sA[r * 192 + p * 8];
                }
                #pragma unroll
                for (int nt = 0; nt < 4; ++nt) {
                    int r = n0w + nt * 16 + l15;
                    b[nt] = *(const bf16x8*)&sB[r * 64 + (((s * 4 + q) ^ r) & 7) * 8];
                }
                #pragma unroll
                for (int mt = 0; mt < 4; ++mt)
                    #pragma unroll
                    for (int nt = 0; nt < 4; ++nt)
                        acc[mt][nt] = MFMA16(a[mt], b[nt], acc[mt][nt]);
            }
        }

        #pragma unroll
        for (int nt = 0; nt < 4; ++nt) {
            float mx = 0.f;                            // relu folded into 0-init
            #pragma unroll
            for (int mt = 0; mt < 4; ++mt)
                #pragma unroll
                for (int r = 0; r < 4; ++r) mx = fmaxf(mx, acc[mt][nt][r]);
            mx = fmaxf(mx, __shfl_xor(mx, 16, 64));
            mx = fmaxf(mx, __shfl_xor(mx, 32, 64));
            if (q == 0) {
                int col = bn * 128 + n0w + nt * 16 + l15;
                atomicMax(&g[col], __float_as_int(mx));
            }
        }
    }
}

// ---------------------------------------------------------------------------
// k4: classifier head, pure f32 (matches np f32 reference). One wave per row.
// ---------------------------------------------------------------------------
__global__ void k4_f1(const float* __restrict__ wf1)
{
    int r = blockIdx.x, l = threadIdx.x;
    float s = 0.f;
    #pragma unroll
    for (int i = 0; i < 16; ++i) s += wf1[r * 1024 + i * 64 + l] * g_buf[i * 64 + l];
    #pragma unroll
    for (int o = 32; o; o >>= 1) s += __shfl_down(s, o, 64);
    if (!l) f1_buf[r] = fmaxf(s, 0.f);
}
__global__ void k4_f2(const float* __restrict__ wf2)
{
    int r = blockIdx.x, l = threadIdx.x;
    float s = 0.f;
    #pragma unroll
    for (int i = 0; i < 8; ++i) s += wf2[r * 512 + i * 64 + l] * f1_buf[i * 64 + l];
    #pragma unroll
    for (int o = 32; o; o >>= 1) s += __shfl_down(s, o, 64);
    if (!l) f2_buf[r] = fmaxf(s, 0.f);
}
__global__ void k4_out(const float* __restrict__ wf3, float* __restrict__ out)
{
    int r = blockIdx.x, l = threadIdx.x;
    float s = 0.f;
    #pragma unroll
    for (int i = 0; i < 4; ++i) s += wf3[r * 256 + i * 64 + l] * f2_buf[i * 64 + l];
    #pragma unroll
    for (int o = 32; o; o >>= 1) s += __shfl_down(s, o, 64);
    if (!l) out[r] = s;
}

// ---------------------------------------------------------------------------
extern "C" void kernel_launch(void* const* d_in, const int* in_sizes, int n_in,
                              void* d_out, int out_size, void* d_ws, size_t ws_size,
                              hipStream_t stream)
{
    (void)in_sizes; (void)n_in; (void)out_size; (void)d_ws; (void)ws_size;
    const float* x   = (const float*)d_in[0];
    // d_in[1] = indptr: fixed degree 16, unused
    const int*   idx = (const int*)d_in[2];
    const float* w1  = (const float*)d_in[3];
    const float* w2  = (const float*)d_in[4];
    const float* w3  = (const float*)d_in[5];
    const float* w4  = (const float*)d_in[6];
    const float* w5  = (const float*)d_in[7];
    const float* wf1 = (const float*)d_in[8];
    const float* wf2 = (const float*)d_in[9];
    const float* wf3 = (const float*)d_in[10];

    float* gptr;
    hipGetSymbolAddress((void**)&gptr, HIP_SYMBOL(g_buf));

    k0_zero <<<1, 1024, 0, stream>>>();
    kcvt    <<<816, 256, 0, stream>>>(w3, w4, w5);
    k1_mlp  <<<262144 / 64, 256, 0, stream>>>(x, w1, w2);
    k3_fused<<<262144 / 128, 256, 0, stream>>>(idx, (int*)gptr);
    k4_f1   <<<512, 64, 0, stream>>>(wf1);
    k4_f2   <<<256, 64, 0, stream>>>(wf2);
    k4_out  <<<40, 64, 0, stream>>>(wf3, (float*)d_out);
}